// Round 3
// baseline (105.522 us; speedup 1.0000x reference)
//
#include <hip/hip_runtime.h>
#include <hip/hip_bf16.h>

// QKVAttentionLegacy: qkv (4,3072,1024) fp32, 16 heads, ch=64.
// R11 = R10 with sigma_row keep-mask fixed (0x23 -> 0x33: bit 4 was dropped,
// collapsing K rows 16-31 onto 0-15 and 48-63 onto 32-47 -> absmax 0.73).
// R10 = 32x32x16 MFMA restructure (4x FLOP per LDS byte vs 16x16x32):
//  - 8 waves: t-group g=wave>>1 (32 t-rows), s-half sh=wave&1 (32 of 64 s/tile).
//    Per wave/iter: QK 4 MFMA + 4 ds_read_b128, PV 4 MFMA + 4 ds_read_b128
//    -> per-CU LDS reads halve vs R9, MFMA count halves at 2x size.
//  - sigma-permuted K rows (sigma = swap bits2<->3, self-inverse): QK C-layout
//    reg r, half h then holds s=(r&7)+8h+16(r>>3), so the PV B-frag is
//    pk(p[2d],p[2d+1]) with IDENTICAL reg indices in both halves:
//    no permlane, no LDS round-trip for P at all.
//  - s-split epilogue: partner waves exchange partial O/l via retired LDS once.
// PV one tile behind (fills exp2 latency); V triple-buffered, K double,
// ONE barrier/iter (last skipped). kap swizzles unchanged (verified floors).

typedef __bf16 bf16_8 __attribute__((ext_vector_type(8)));
typedef __bf16 bf16_4 __attribute__((ext_vector_type(4)));
typedef float floatx4 __attribute__((ext_vector_type(4)));
typedef float floatx16 __attribute__((ext_vector_type(16)));

#define NTHREADS 512
#define STR 64               // bf16 elems per LDS row (128 B, swizzle not pad)
#define NSTEPS 16

#if __has_builtin(__builtin_amdgcn_exp2f)
#define EXP2(x) __builtin_amdgcn_exp2f(x)
#else
#define EXP2(x) exp2f(x)
#endif
// (1/8)*log2(e): qk scale + exp->exp2, folded into Q staging (one bf16 rounding).
#define QSCALE 0.18033688011112042f

// LDS: q_s [128][64]bf16 @0 (16384, dead after qf loads)
//      k0 @16384 | k1 @24576 | v0 @32768 | v1 @40960 | v2 @49152 (each 8192)
// epilogue reuse: O-exchange @0 (32KB, over q_s/k0/k1), l-exchange @40960 (in v1;
// safe: final PV reads v0 = tile15%3, retired by barrier before writes)
#define LDS_BYTES 57344

#define ZERO16 (floatx16){0.f,0.f,0.f,0.f,0.f,0.f,0.f,0.f,0.f,0.f,0.f,0.f,0.f,0.f,0.f,0.f}

__device__ __forceinline__ int kap(int row) { return ((row >> 1) + (row >> 4)) & 7; }
// swap bits 2<->3 (keep 0,1,4,5); self-inverse. K s-row -> LDS row relabeling.
__device__ __forceinline__ int sigma_row(int s) {
    return (s & 0x33) | ((s & 4) << 1) | ((s & 8) >> 1);
}

__device__ __forceinline__ unsigned pk_bf16(float a, float b) {
    unsigned r;
    asm("v_cvt_pk_bf16_f32 %0, %1, %2" : "=v"(r) : "v"(a), "v"(b));
    return r;
}

union U8 { unsigned u[4]; bf16_8 v; };

__device__ __forceinline__ void write_k(__bf16* kn, const float4* r, int si, int sG) {
    #pragma unroll
    for (int rr = 0; rr < 4; ++rr) {
        int srow = si * 4 + rr;
        int m = sigma_row(srow);          // permuted LDS row
        bf16_4 w;
        w[0] = (__bf16)((const float*)&r[0])[rr];
        w[1] = (__bf16)((const float*)&r[1])[rr];
        w[2] = (__bf16)((const float*)&r[2])[rr];
        w[3] = (__bf16)((const float*)&r[3])[rr];
        *(bf16_4*)&kn[m * STR + ((sG ^ (kap(m) << 1)) << 2)] = w;
    }
}
__device__ __forceinline__ void write_v(__bf16* vn, const float4* r, int si, int c0) {
    #pragma unroll
    for (int jj = 0; jj < 4; ++jj) {
        int c = c0 + jj;
        bf16_4 w;
        w[0] = (__bf16)r[jj].x; w[1] = (__bf16)r[jj].y;
        w[2] = (__bf16)r[jj].z; w[3] = (__bf16)r[jj].w;
        *(bf16_4*)&vn[c * STR + ((si ^ (kap(c) << 1)) << 2)] = w;
    }
}

__global__ __launch_bounds__(NTHREADS, 4)
void attn_kernel(const float* __restrict__ qkv, float* __restrict__ out) {
    __shared__ char smem[LDS_BYTES];
    __bf16* q_s = (__bf16*)smem;
    __bf16* k0  = (__bf16*)(smem + 16384);
    __bf16* k1  = (__bf16*)(smem + 24576);
    __bf16* v0  = (__bf16*)(smem + 32768);
    __bf16* v1  = (__bf16*)(smem + 40960);
    __bf16* v2  = (__bf16*)(smem + 49152);

    const int tid  = threadIdx.x;
    const int wave = tid >> 6;
    const int lane = tid & 63;
    const int hv   = lane >> 5;          // lane half (k-octet select)
    const int l31  = lane & 31;
    const int g    = wave >> 1;          // t-group: rows [32g, 32g+32)
    const int sh   = wave & 1;           // s-half: [32sh, 32sh+32) of each tile

    const int bx = blockIdx.x;           // 512 = 8 t-tiles * 64 bh (bh fastest -> XCD)
    const int bh = bx & 63;
    const int t0 = (bx >> 6) << 7;       // *128

    const float* qg = qkv + (size_t)bh * 196608;
    const float* kg = qg + 65536;
    const float* vg = qg + 131072;

    // staging split: waves 0-3 stage K, waves 4-7 stage V
    const int sv = tid >> 8;
    const int st = tid & 255;
    const int si = st & 15;
    const int sG = st >> 4;
    const int c0 = sG << 2;
    const float* gsrc = sv ? vg : kg;

    // ---- prologue: Q [128t][64c] scaled+transposed+swizzled ----
    {
        const int cG = tid >> 5;         // 0..15
        const int ti = tid & 31;
        float4 q4[4];
        #pragma unroll
        for (int jj = 0; jj < 4; ++jj)
            q4[jj] = *(const float4*)(qg + (cG * 4 + jj) * 1024 + t0 + ti * 4);
        #pragma unroll
        for (int rr = 0; rr < 4; ++rr) {
            int trow = ti * 4 + rr;
            bf16_4 w;
            w[0] = (__bf16)(((const float*)&q4[0])[rr] * QSCALE);
            w[1] = (__bf16)(((const float*)&q4[1])[rr] * QSCALE);
            w[2] = (__bf16)(((const float*)&q4[2])[rr] * QSCALE);
            w[3] = (__bf16)(((const float*)&q4[3])[rr] * QSCALE);
            *(bf16_4*)&q_s[trow * STR + ((cG ^ (kap(trow) << 1)) << 2)] = w;
        }
    }
    // ---- K/V tile 0 ----
    {
        float4 r4[4];
        #pragma unroll
        for (int jj = 0; jj < 4; ++jj)
            r4[jj] = *(const float4*)(gsrc + (c0 + jj) * 1024 + si * 4);
        if (!sv) write_k(k0, r4, si, sG);
        else     write_v(v0, r4, si, c0);
    }
    __syncthreads();

    // Q B-frags [k=c][n=t] for this wave's 32-t tile: 4 c-chunks, in regs all loop
    bf16_8 qf[4];
    {
        int row = g * 32 + l31;
        int x = kap(row);
        #pragma unroll
        for (int kc = 0; kc < 4; ++kc)
            qf[kc] = *(const bf16_8*)&q_s[row * STR + ((((kc << 1) | hv) ^ x) << 3)];
    }

    floatx16 O0 = ZERO16, O1 = ZERO16;   // c-tiles [0,32), [32,64); partial over sh
    float l = 0.f;
    bf16_8 pfp0, pfp1;                   // P-frags of tile is-1 (carried)
    int vprev = 2, vcur = 0, vnext = 1;

    const int krow = sh * 32 + l31;      // K A-frag LDS row (sigma applied on write)
    const int kx   = kap(krow);
    const int vx0  = kap(l31);
    const int vx1  = kap(32 + l31);

    for (int is = 0; is < NSTEPS; ++is) {
        const __bf16* kb = (is & 1) ? k1 : k0;

        // global prefetch of tile is+1
        float4 pr[4];
        if (is < NSTEPS - 1) {
            const int s0n = (is + 1) * 64;
            #pragma unroll
            for (int jj = 0; jj < 4; ++jj)
                pr[jj] = *(const float4*)(gsrc + (c0 + jj) * 1024 + s0n + si * 4);
        }

        // ---- S^T tile [32s][32t]: 4 chained MFMAs over c ----
        floatx16 St = ZERO16;
        #pragma unroll
        for (int kc = 0; kc < 4; ++kc) {
            bf16_8 kf = *(const bf16_8*)&kb[krow * STR + ((((kc << 1) | hv) ^ kx) << 3)];
            St = __builtin_amdgcn_mfma_f32_32x32x16_bf16(kf, qf[kc], St, 0, 0, 0);
        }

        // ---- P = exp2(S^T) -> packed B-frags, fully in-register (sigma magic) ----
        U8 w0, w1;
        #pragma unroll
        for (int d = 0; d < 4; ++d) {
            float pa = EXP2(St[2 * d]);
            float pb = EXP2(St[2 * d + 1]);
            float pc = EXP2(St[8 + 2 * d]);
            float pd = EXP2(St[8 + 2 * d + 1]);
            l += (pa + pb) + (pc + pd);
            w0.u[d] = pk_bf16(pa, pb);
            w1.u[d] = pk_bf16(pc, pd);
        }
        bf16_8 pfn0 = w0.v, pfn1 = w1.v;

        // ---- PV_{is-1} (independent of QK_is/softmax_is -> fills latency) ----
        if (is > 0) {
            const __bf16* vp = (vprev == 0) ? v0 : ((vprev == 1) ? v1 : v2);
            {
                int vrow = l31;
                bf16_8 vfa = *(const bf16_8*)&vp[vrow * STR + ((((sh << 2) | hv) ^ vx0) << 3)];
                O0 = __builtin_amdgcn_mfma_f32_32x32x16_bf16(vfa, pfp0, O0, 0, 0, 0);
                bf16_8 vfb = *(const bf16_8*)&vp[vrow * STR + ((((sh << 2) | 2 | hv) ^ vx0) << 3)];
                O0 = __builtin_amdgcn_mfma_f32_32x32x16_bf16(vfb, pfp1, O0, 0, 0, 0);
            }
            {
                int vrow = 32 + l31;
                bf16_8 vfa = *(const bf16_8*)&vp[vrow * STR + ((((sh << 2) | hv) ^ vx1) << 3)];
                O1 = __builtin_amdgcn_mfma_f32_32x32x16_bf16(vfa, pfp0, O1, 0, 0, 0);
                bf16_8 vfb = *(const bf16_8*)&vp[vrow * STR + ((((sh << 2) | 2 | hv) ^ vx1) << 3)];
                O1 = __builtin_amdgcn_mfma_f32_32x32x16_bf16(vfb, pfp1, O1, 0, 0, 0);
            }
        }
        pfp0 = pfn0; pfp1 = pfn1;

        // ---- staging of tile is+1 ----
        if (is < NSTEPS - 1) {
            if (!sv) {
                __bf16* kn = (is & 1) ? k0 : k1;
                write_k(kn, pr, si, sG);
            } else {
                __bf16* vn = (vnext == 0) ? v0 : ((vnext == 1) ? v1 : v2);
                write_v(vn, pr, si, c0);
            }
            __syncthreads();             // publish is+1, retire reads of K_is / V_{is-1}
        }
        vprev = vcur; vcur = vnext; vnext = (vnext == 2) ? 0 : vnext + 1;
    }

    // ---- final PV for tile 15 (buffer v0 = vprev after 16 rotations) ----
    {
        const __bf16* vp = (vprev == 0) ? v0 : ((vprev == 1) ? v1 : v2);
        {
            int vrow = l31;
            bf16_8 vfa = *(const bf16_8*)&vp[vrow * STR + ((((sh << 2) | hv) ^ vx0) << 3)];
            O0 = __builtin_amdgcn_mfma_f32_32x32x16_bf16(vfa, pfp0, O0, 0, 0, 0);
            bf16_8 vfb = *(const bf16_8*)&vp[vrow * STR + ((((sh << 2) | 2 | hv) ^ vx0) << 3)];
            O0 = __builtin_amdgcn_mfma_f32_32x32x16_bf16(vfb, pfp1, O0, 0, 0, 0);
        }
        {
            int vrow = 32 + l31;
            bf16_8 vfa = *(const bf16_8*)&vp[vrow * STR + ((((sh << 2) | hv) ^ vx1) << 3)];
            O1 = __builtin_amdgcn_mfma_f32_32x32x16_bf16(vfa, pfp0, O1, 0, 0, 0);
            bf16_8 vfb = *(const bf16_8*)&vp[vrow * STR + ((((sh << 2) | 2 | hv) ^ vx1) << 3)];
            O1 = __builtin_amdgcn_mfma_f32_32x32x16_bf16(vfb, pfp1, O1, 0, 0, 0);
        }
    }

    // ---- epilogue: combine s-halves (partner waves), normalize, store O^T ----
    l += __shfl_xor(l, 32);              // add other lane-half's s-contribution

    __syncthreads();                     // all PV reads retired; repurpose LDS
    float* xo = (float*)smem;            // 4 groups x 8KB partial-O exchange
    float* xl = (float*)(smem + 40960);  // l exchange (v1 area, not vprev=v0)
    if (sh == 1) {
        float* b = xo + g * 2048;
        #pragma unroll
        for (int rq = 0; rq < 4; ++rq) {
            floatx4 a0 = {O0[4 * rq], O0[4 * rq + 1], O0[4 * rq + 2], O0[4 * rq + 3]};
            *(floatx4*)&b[(rq * 64 + lane) * 4] = a0;
            floatx4 a1 = {O1[4 * rq], O1[4 * rq + 1], O1[4 * rq + 2], O1[4 * rq + 3]};
            *(floatx4*)&b[((4 + rq) * 64 + lane) * 4] = a1;
        }
        xl[g * 64 + lane] = l;
    }
    __syncthreads();
    if (sh == 0) {
        const float* b = xo + g * 2048;
        const float lt = l + xl[g * 64 + lane];
        const float linv = 1.0f / lt;
        float* og = out + (size_t)bh * 65536 + t0 + g * 32;
        #pragma unroll
        for (int rq = 0; rq < 4; ++rq) {
            floatx4 a0 = *(const floatx4*)&b[(rq * 64 + lane) * 4];
            floatx4 a1 = *(const floatx4*)&b[((4 + rq) * 64 + lane) * 4];
            #pragma unroll
            for (int j = 0; j < 4; ++j) {
                int cl = j + 8 * rq + 4 * hv;       // C-layout row within c-tile
                og[cl * 1024 + l31] = (O0[4 * rq + j] + a0[j]) * linv;
                og[(32 + cl) * 1024 + l31] = (O1[4 * rq + j] + a1[j]) * linv;
            }
        }
    }
}

extern "C" void kernel_launch(void* const* d_in, const int* in_sizes, int n_in,
                              void* d_out, int out_size, void* d_ws, size_t ws_size,
                              hipStream_t stream) {
    const float* qkv = (const float*)d_in[0];
    float* out = (float*)d_out;
    attn_kernel<<<dim3(512), dim3(NTHREADS), 0, stream>>>(qkv, out);
}